// Round 5
// baseline (1319.598 us; speedup 1.0000x reference)
//
#include <hip/hip_runtime.h>
#include <hip/hip_bf16.h>

// RGCN classifier, MI355X. Round 5: no CSR — single-pass bucket fill (64 nodes/
// bucket, rank-from-atomic doubles as count), gather via LDS fp32 accumulators,
// layer-2 gather fuses the per-graph max pool (h2 never materialized).
// ws layout (bytes):
//   XW     @ 0          : 65536*1152*2 = 150,994,944  (bf16 [node][1152])
//   hb     @ 150994944  : 16,777,216   (h bf16)
//   h1b    @ 167772160  : 16,777,216
//   Wt1c   @ 184549376  : 294,912      (bf16 [tile*128+n][k])
//   Wt2c   @ 184844288  : 294,912
//   cnt    @ 185139200  : 4,096        (int per bucket)
//   recbuf @ 185143296  : 4,718,592    (uint, 1152 slots per bucket)
//   partial@ 189861888  : 524,288      (f32 [1024][128] pool partials)
// total ~190.4 MB

#define N_NODES 65536
#define N_EDGES 786432
#define DIM 128
#define NT 9
#define XW_LD (NT * DIM) /* 1152 */
#define N_GRAPHS 64
#define NBUCKET 1024
#define BSLOTS 1152

typedef unsigned int uint;
typedef unsigned short ushort;
typedef __attribute__((ext_vector_type(8))) short short8;
typedef __attribute__((ext_vector_type(4))) float f32x4;

__device__ inline ushort f2b(float f) {
  uint u = __float_as_uint(f);
  u += 0x7fff + ((u >> 16) & 1);   // RNE
  return (ushort)(u >> 16);
}
__device__ inline float b2f(ushort h) { return __uint_as_float(((uint)h) << 16); }
__device__ inline float blo(uint v) { return __uint_as_float(v << 16); }
__device__ inline float bhi(uint v) { return __uint_as_float(v & 0xffff0000u); }

__device__ inline void gl_lds16(const void* g, void* l) {
  __builtin_amdgcn_global_load_lds(
      (const __attribute__((address_space(1))) unsigned int*)g,
      (__attribute__((address_space(3))) unsigned int*)l, 16, 0, 0);
}

// ---------------- conversions ----------------
__global__ __launch_bounds__(256) void f32_to_bf16_vec(const float* __restrict__ x,
                                                       ushort* __restrict__ y, int n4) {
  int i = blockIdx.x * 256 + threadIdx.x;
  if (i >= n4) return;
  float4 v = ((const float4*)x)[i];
  ushort4 o;
  o.x = f2b(v.x); o.y = f2b(v.y); o.z = f2b(v.z); o.w = f2b(v.w);
  ((ushort4*)y)[i] = o;
}

// Weights -> bf16 [tile*128+n][k] (B^T tiles, contiguous per output-col tile)
__global__ __launch_bounds__(256) void wconv_all(const float* __restrict__ W1,
                                                 const float* __restrict__ W1s,
                                                 const float* __restrict__ W2,
                                                 const float* __restrict__ W2s,
                                                 ushort* __restrict__ Wt1,
                                                 ushort* __restrict__ Wt2) {
  int b = blockIdx.x;  // 0..17
  const float* S;
  ushort* D;
  int tile;
  if (b < 9) { D = Wt1; tile = b; S = (b < 8) ? (W1 + (size_t)b * 16384) : W1s; }
  else       { D = Wt2; tile = b - 9; S = (tile < 8) ? (W2 + (size_t)tile * 16384) : W2s; }
  for (int i = threadIdx.x; i < 16384; i += 256) {
    int n = i >> 7, k = i & 127;
    D[((size_t)tile * 128 + n) * 128 + k] = f2b(S[k * 128 + n]);
  }
}

// ---------------- single-pass edge bucketing ----------------
// rec = (src*576 + et*64) << 6 | (dst & 63); bucket = dst >> 6.
// rank from atomicAdd doubles as the bucket count (no hist/scan).
__global__ __launch_bounds__(256) void fill_direct(const int* __restrict__ src,
                                                   const int* __restrict__ dst,
                                                   const int* __restrict__ et,
                                                   int* __restrict__ cnt,
                                                   uint* __restrict__ recbuf) {
  int e = blockIdx.x * 256 + threadIdx.x;
  if (e >= N_EDGES) return;
  int d = dst[e];
  int b = d >> 6;
  int r = atomicAdd(&cnt[b], 1);
  if (r < BSLOTS)
    recbuf[(size_t)b * BSLOTS + r] =
        (((uint)src[e] * 576u + (uint)et[e] * 64u) << 6) | (uint)(d & 63);
}

// ---------------- GEMM: XW[65536,1152] = hb[65536,128] @ Wcat ----------------
// 128x128 tile, K=128 single-stage, XOR-swizzled LDS staging (validated).
__global__ __launch_bounds__(256) void gemm128(const ushort* __restrict__ A,
                                               const ushort* __restrict__ Bt,
                                               ushort* __restrict__ C, int ldc) {
  __shared__ char lds[65536];
  const int bm = blockIdx.x, bn = blockIdx.y;
  const char* Ag = (const char*)(A + (size_t)bm * 128 * 128);
  const char* Bg = (const char*)(Bt + (size_t)bn * 128 * 128);
  const int tid = threadIdx.x;
  const int wv = tid >> 6, ln = tid & 63;

#pragma unroll
  for (int it = 0; it < 8; ++it) {
    int chunk = it * 4096 + wv * 1024;          // wave-uniform LDS base
    int p = chunk + ln * 16;                    // linear lds byte pos
    int ps = p ^ (((p >> 8) & 7) << 4);         // inverse-swizzled global source
    gl_lds16(Ag + ps, lds + chunk);
    gl_lds16(Bg + ps, lds + 32768 + chunk);
  }
  asm volatile("s_waitcnt vmcnt(0)" ::: "memory");
  __syncthreads();

  const int wm = wv >> 1, wn = wv & 1;
  const int lr = ln & 15, kq = ln >> 4;
  f32x4 acc[4][4];
#pragma unroll
  for (int m = 0; m < 4; ++m)
#pragma unroll
    for (int n = 0; n < 4; ++n) acc[m][n] = (f32x4){0.f, 0.f, 0.f, 0.f};

#pragma unroll
  for (int kk = 0; kk < 4; ++kk) {
    const int kb = kk * 64 + kq * 16;
    short8 a[4], b[4];
#pragma unroll
    for (int m = 0; m < 4; ++m) {
      int row = wm * 64 + m * 16 + lr;
      int off = row * 256 + kb;
      a[m] = *(const short8*)(lds + (off ^ ((row & 7) << 4)));
    }
#pragma unroll
    for (int n = 0; n < 4; ++n) {
      int col = wn * 64 + n * 16 + lr;
      int off = col * 256 + kb;
      b[n] = *(const short8*)(lds + 32768 + (off ^ ((col & 7) << 4)));
    }
#pragma unroll
    for (int m = 0; m < 4; ++m)
#pragma unroll
      for (int n = 0; n < 4; ++n)
        acc[m][n] = __builtin_amdgcn_mfma_f32_16x16x32_bf16(a[m], b[n], acc[m][n], 0, 0, 0);
  }

#pragma unroll
  for (int m = 0; m < 4; ++m) {
    int row0 = bm * 128 + wm * 64 + m * 16 + kq * 4;
#pragma unroll
    for (int n = 0; n < 4; ++n) {
      int col = bn * 128 + wn * 64 + n * 16 + lr;
#pragma unroll
      for (int e = 0; e < 4; ++e)
        C[(size_t)(row0 + e) * ldc + col] = f2b(acc[m][n][e]);
    }
  }
}

// ---------------- gather_tile: 64-node bucket, LDS fp32 accumulation ----------------
// Lane ln owns dims {ln, 64+ln} -> LDS atomics 2-lanes/bank (conflict-free).
// Epilogue fuses self + bias + ReLU; POOL variant also fuses per-bucket max pool
// and skips the h-out write entirely.
template <bool POOL>
__global__ __launch_bounds__(256) void gather_tile(const ushort* __restrict__ XWs,
                                                   const uint* __restrict__ recbuf,
                                                   const int* __restrict__ cnt,
                                                   const float* __restrict__ bias,
                                                   uint* __restrict__ hout,
                                                   float* __restrict__ partial) {
  __shared__ float acc[64][128];
  __shared__ float pm[4][128];
  const int b = blockIdx.x;
  const int tid = threadIdx.x, w = tid >> 6, ln = tid & 63;
  const uint* XWu = (const uint*)XWs;

  float4* az = (float4*)&acc[0][0];
  for (int i = tid; i < 64 * 128 / 4; i += 256) az[i] = (float4){0.f, 0.f, 0.f, 0.f};

  float2 bv = ((const float2*)bias)[ln];
  int n = cnt[b];
  if (n > BSLOTS) n = BSLOTS;
  n = __builtin_amdgcn_readfirstlane(n);
  const uint* rb = recbuf + (size_t)b * BSLOTS;
  __syncthreads();

  for (int base = w * 64; base < n; base += 256) {
    int nc = n - base;
    if (nc > 64) nc = 64;
    uint rv = rb[base + (ln < nc ? ln : nc - 1)];  // wave preload of 64 recs
    int i = 0;
    for (; i + 8 <= nc; i += 8) {
      float x0[8], x1[8];
      uint nl[8];
#pragma unroll
      for (int j = 0; j < 8; ++j) {
        uint rec = (uint)__builtin_amdgcn_readlane((int)rv, i + j);
        uint so = (rec >> 6) * 2;       // ushort offset of XW row
        nl[j] = rec & 63u;
        x0[j] = b2f(XWs[(size_t)so + ln]);
        x1[j] = b2f(XWs[(size_t)so + 64 + ln]);
      }
#pragma unroll
      for (int j = 0; j < 8; ++j) {
        atomicAdd(&acc[nl[j]][ln], x0[j]);
        atomicAdd(&acc[nl[j]][64 + ln], x1[j]);
      }
    }
    for (; i < nc; ++i) {
      uint rec = (uint)__builtin_amdgcn_readlane((int)rv, i);
      uint so = (rec >> 6) * 2;
      uint nl = rec & 63u;
      float x0 = b2f(XWs[(size_t)so + ln]);
      float x1 = b2f(XWs[(size_t)so + 64 + ln]);
      atomicAdd(&acc[nl][ln], x0);
      atomicAdd(&acc[nl][64 + ln], x1);
    }
  }
  __syncthreads();

  float m0 = 0.f, m1 = 0.f;  // post-ReLU >= 0
#pragma unroll
  for (int k = 0; k < 16; ++k) {
    int nlo = w * 16 + k;
    int node = b * 64 + nlo;
    float2 a = *(const float2*)&acc[nlo][ln * 2];
    uint sv = XWu[(size_t)node * 576 + 512 + ln];  // self tile
    float r0 = fmaxf(a.x + blo(sv) + bv.x, 0.f);
    float r1 = fmaxf(a.y + bhi(sv) + bv.y, 0.f);
    if (POOL) {
      m0 = fmaxf(m0, r0);
      m1 = fmaxf(m1, r1);
    } else {
      hout[(size_t)node * 64 + ln] = (uint)f2b(r0) | ((uint)f2b(r1) << 16);
    }
  }
  if (POOL) {
    pm[w][ln * 2] = m0;
    pm[w][ln * 2 + 1] = m1;
    __syncthreads();
    if (tid < 128) {
      float m = fmaxf(fmaxf(pm[0][tid], pm[1][tid]), fmaxf(pm[2][tid], pm[3][tid]));
      partial[(size_t)b * 128 + tid] = m;
    }
  }
}

// ---------------- classifier: pooled = max over 16 bucket-partials; out = pooled@Wc+bc
__global__ __launch_bounds__(128) void classify(const float* __restrict__ partial,
                                                const float* __restrict__ Wc,
                                                const float* __restrict__ bc,
                                                float* __restrict__ out) {
  __shared__ float pooled[128];
  int g = blockIdx.x, tid = threadIdx.x;
  const float* p = partial + (size_t)g * 16 * 128;
  float m = 0.f;
#pragma unroll
  for (int i = 0; i < 16; ++i) m = fmaxf(m, p[i * 128 + tid]);
  pooled[tid] = m;
  __syncthreads();
  if (tid < 10) {
    float s = bc[tid];
    for (int d = 0; d < DIM; ++d) s += pooled[d] * Wc[d * 10 + tid];
    out[g * 10 + tid] = s;
  }
}

extern "C" void kernel_launch(void* const* d_in, const int* in_sizes, int n_in,
                              void* d_out, int out_size, void* d_ws, size_t ws_size,
                              hipStream_t stream) {
  const float* h       = (const float*)d_in[0];
  const float* W1      = (const float*)d_in[1];
  const float* W1_self = (const float*)d_in[2];
  const float* b1      = (const float*)d_in[3];
  const float* W2      = (const float*)d_in[4];
  const float* W2_self = (const float*)d_in[5];
  const float* b2      = (const float*)d_in[6];
  const float* Wc      = (const float*)d_in[7];
  const float* bc      = (const float*)d_in[8];
  const int* src   = (const int*)d_in[9];
  const int* dst   = (const int*)d_in[10];
  const int* etype = (const int*)d_in[11];
  float* out = (float*)d_out;

  char* ws = (char*)d_ws;
  ushort* XW     = (ushort*)(ws);
  ushort* hb     = (ushort*)(ws + 150994944);
  ushort* h1b    = (ushort*)(ws + 167772160);
  ushort* Wt1c   = (ushort*)(ws + 184549376);
  ushort* Wt2c   = (ushort*)(ws + 184844288);
  int*    cnt    = (int*)(ws + 185139200);
  uint*   recbuf = (uint*)(ws + 185143296);
  float*  partial= (float*)(ws + 189861888);

  const int n4_h = N_NODES * DIM / 4;        // 2,097,152
  const int g_h = n4_h / 256;                // 8192
  const int g_edge = (N_EDGES + 255) / 256;  // 3072
  dim3 gemm_grid(N_NODES / 128, NT);

  // --- prep ---
  f32_to_bf16_vec<<<g_h, 256, 0, stream>>>(h, hb, n4_h);
  wconv_all<<<18, 256, 0, stream>>>(W1, W1_self, W2, W2_self, Wt1c, Wt2c);

  // --- edge bucketing (shared by both layers) ---
  hipMemsetAsync(cnt, 0, NBUCKET * sizeof(int), stream);
  fill_direct<<<g_edge, 256, 0, stream>>>(src, dst, etype, cnt, recbuf);

  // --- layer 1: XW = hb @ Wcat1 ; h1 = relu(gather + self + b1) ---
  gemm128<<<gemm_grid, 256, 0, stream>>>(hb, Wt1c, XW, XW_LD);
  gather_tile<false><<<NBUCKET, 256, 0, stream>>>((const ushort*)XW, recbuf, cnt, b1,
                                                  (uint*)h1b, partial);

  // --- layer 2: pool fused into gather epilogue; h2 never materialized ---
  gemm128<<<gemm_grid, 256, 0, stream>>>(h1b, Wt2c, XW, XW_LD);
  gather_tile<true><<<NBUCKET, 256, 0, stream>>>((const ushort*)XW, recbuf, cnt, b2,
                                                 (uint*)h1b, partial);

  // --- classify ---
  classify<<<N_GRAPHS, 128, 0, stream>>>(partial, Wc, bc, out);

  (void)in_sizes; (void)n_in; (void)out_size; (void)ws_size;
}

// Round 6
// 262.302 us; speedup vs baseline: 5.0308x; 5.0308x over previous
//
#include <hip/hip_runtime.h>
#include <hip/hip_bf16.h>

// RGCN classifier, MI355X. Round 6: round-4 structure (transform-first GEMM +
// wave-per-node CSR gather) with XCD-sliced CSR build: scatter writes are
// destination-sliced so each slice's meta/deg region stays in one XCD's L2
// (kills the 53MB write-allocate churn of the unsliced fill_meta).
// ws layout (bytes):
//   XW    @ 0          : 65536*1152*2 = 150,994,944  (bf16 [node][1152])
//   hb    @ 150994944  : 16,777,216   (h bf16)
//   h1b   @ 167772160  : 16,777,216
//   hb2   @ 184549376  : 16,777,216
//   Wt1c  @ 201326592  : 294,912      (bf16 [tile*128+n][k])
//   Wt2c  @ 201621504  : 294,912
//   deg   @ 201916416  : 262,144
//   offs  @ 202178560  : 262,144
//   cursor@ 202440704  : 262,144
//   bsum  @ 202702848  : 1,024
//   meta  @ 202703872  : 3,145,728    (uint offset src*576 + et*64, CSR by dst)
//   partial@205849600  : 262,144
// total ~206.1 MB

#define N_NODES 65536
#define N_EDGES 786432
#define DIM 128
#define NT 9
#define XW_LD (NT * DIM) /* 1152 */
#define N_GRAPHS 64

typedef unsigned int uint;
typedef unsigned short ushort;
typedef __attribute__((ext_vector_type(8))) short short8;
typedef __attribute__((ext_vector_type(4))) float f32x4;

__device__ inline ushort f2b(float f) {
  uint u = __float_as_uint(f);
  u += 0x7fff + ((u >> 16) & 1);   // RNE
  return (ushort)(u >> 16);
}
__device__ inline float b2f(ushort h) { return __uint_as_float(((uint)h) << 16); }
__device__ inline float blo(uint v) { return __uint_as_float(v << 16); }
__device__ inline float bhi(uint v) { return __uint_as_float(v & 0xffff0000u); }

__device__ inline void gl_lds16(const void* g, void* l) {
  __builtin_amdgcn_global_load_lds(
      (const __attribute__((address_space(1))) unsigned int*)g,
      (__attribute__((address_space(3))) unsigned int*)l, 16, 0, 0);
}

// ---------------- conversions ----------------
__global__ __launch_bounds__(256) void f32_to_bf16_vec(const float* __restrict__ x,
                                                       ushort* __restrict__ y, int n4) {
  int i = blockIdx.x * 256 + threadIdx.x;
  if (i >= n4) return;
  float4 v = ((const float4*)x)[i];
  ushort4 o;
  o.x = f2b(v.x); o.y = f2b(v.y); o.z = f2b(v.z); o.w = f2b(v.w);
  ((ushort4*)y)[i] = o;
}

// Weights -> bf16 [tile*128+n][k] (B^T tiles, contiguous per output-col tile)
__global__ __launch_bounds__(256) void wconv_all(const float* __restrict__ W1,
                                                 const float* __restrict__ W1s,
                                                 const float* __restrict__ W2,
                                                 const float* __restrict__ W2s,
                                                 ushort* __restrict__ Wt1,
                                                 ushort* __restrict__ Wt2) {
  int b = blockIdx.x;  // 0..17
  const float* S;
  ushort* D;
  int tile;
  if (b < 9) { D = Wt1; tile = b; S = (b < 8) ? (W1 + (size_t)b * 16384) : W1s; }
  else       { D = Wt2; tile = b - 9; S = (tile < 8) ? (W2 + (size_t)tile * 16384) : W2s; }
  for (int i = threadIdx.x; i < 16384; i += 256) {
    int n = i >> 7, k = i & 127;
    D[((size_t)tile * 128 + n) * 128 + k] = f2b(S[k * 128 + n]);
  }
}

// ---------------- CSR build (XCD-sliced scatters) ----------------
// slice = blockIdx.x & 7 maps round-robin onto the 8 XCDs; each slice owns
// dst range [slice*8192, (slice+1)*8192) so its deg/meta region is L2-local.
__global__ __launch_bounds__(256) void hist_sliced(const int* __restrict__ dst,
                                                   int* __restrict__ deg) {
  int slice = blockIdx.x & 7;
  int e = (blockIdx.x >> 3) * 256 + threadIdx.x;
  if (e >= N_EDGES) return;
  int d = dst[e];
  if ((d >> 13) != slice) return;
  atomicAdd(&deg[d], 1);
}
__global__ __launch_bounds__(256) void scan_block(const int* __restrict__ deg,
                                                  int* __restrict__ offs,
                                                  int* __restrict__ bsum) {
  __shared__ int s[256];
  int t = threadIdx.x, i = blockIdx.x * 256 + t;
  int v = deg[i];
  s[t] = v; __syncthreads();
  for (int d = 1; d < 256; d <<= 1) {
    int x = (t >= d) ? s[t - d] : 0; __syncthreads();
    s[t] += x; __syncthreads();
  }
  offs[i] = s[t] - v;
  if (t == 255) bsum[blockIdx.x] = s[t];
}
__global__ __launch_bounds__(256) void scan_bsum(int* __restrict__ bsum) {
  __shared__ int s[256];
  int t = threadIdx.x;
  int v = bsum[t];
  s[t] = v; __syncthreads();
  for (int d = 1; d < 256; d <<= 1) {
    int x = (t >= d) ? s[t - d] : 0; __syncthreads();
    s[t] += x; __syncthreads();
  }
  bsum[t] = s[t] - v;
}
__global__ __launch_bounds__(256) void add_offs(int* __restrict__ offs,
                                                const int* __restrict__ bsum,
                                                int* __restrict__ cursor) {
  int i = blockIdx.x * 256 + threadIdx.x;
  int o = offs[i] + bsum[blockIdx.x];
  offs[i] = o; cursor[i] = o;
}
// meta = uint-offset of XW[src, etype*128] in the u32 view: src*576 + et*64
__global__ __launch_bounds__(256) void fill_meta_sliced(const int* __restrict__ src,
                                                        const int* __restrict__ dst,
                                                        const int* __restrict__ et,
                                                        int* __restrict__ cursor,
                                                        uint* __restrict__ meta) {
  int slice = blockIdx.x & 7;
  int e = (blockIdx.x >> 3) * 256 + threadIdx.x;
  if (e >= N_EDGES) return;
  int d = dst[e];
  if ((d >> 13) != slice) return;
  int p = atomicAdd(&cursor[d], 1);
  meta[p] = (uint)src[e] * 576u + (uint)et[e] * 64u;
}

// ---------------- GEMM: XW[65536,1152] = hb[65536,128] @ Wcat ----------------
// 128x128 tile, K=128 single-stage, XOR-swizzled LDS staging (validated).
__global__ __launch_bounds__(256) void gemm128(const ushort* __restrict__ A,
                                               const ushort* __restrict__ Bt,
                                               ushort* __restrict__ C, int ldc) {
  __shared__ char lds[65536];
  const int bm = blockIdx.x, bn = blockIdx.y;
  const char* Ag = (const char*)(A + (size_t)bm * 128 * 128);
  const char* Bg = (const char*)(Bt + (size_t)bn * 128 * 128);
  const int tid = threadIdx.x;
  const int wv = tid >> 6, ln = tid & 63;

#pragma unroll
  for (int it = 0; it < 8; ++it) {
    int chunk = it * 4096 + wv * 1024;          // wave-uniform LDS base
    int p = chunk + ln * 16;                    // linear lds byte pos
    int ps = p ^ (((p >> 8) & 7) << 4);         // inverse-swizzled global source
    gl_lds16(Ag + ps, lds + chunk);
    gl_lds16(Bg + ps, lds + 32768 + chunk);
  }
  asm volatile("s_waitcnt vmcnt(0)" ::: "memory");
  __syncthreads();

  const int wm = wv >> 1, wn = wv & 1;
  const int lr = ln & 15, kq = ln >> 4;
  f32x4 acc[4][4];
#pragma unroll
  for (int m = 0; m < 4; ++m)
#pragma unroll
    for (int n = 0; n < 4; ++n) acc[m][n] = (f32x4){0.f, 0.f, 0.f, 0.f};

#pragma unroll
  for (int kk = 0; kk < 4; ++kk) {
    const int kb = kk * 64 + kq * 16;
    short8 a[4], b[4];
#pragma unroll
    for (int m = 0; m < 4; ++m) {
      int row = wm * 64 + m * 16 + lr;
      int off = row * 256 + kb;
      a[m] = *(const short8*)(lds + (off ^ ((row & 7) << 4)));
    }
#pragma unroll
    for (int n = 0; n < 4; ++n) {
      int col = wn * 64 + n * 16 + lr;
      int off = col * 256 + kb;
      b[n] = *(const short8*)(lds + 32768 + (off ^ ((col & 7) << 4)));
    }
#pragma unroll
    for (int m = 0; m < 4; ++m)
#pragma unroll
      for (int n = 0; n < 4; ++n)
        acc[m][n] = __builtin_amdgcn_mfma_f32_16x16x32_bf16(a[m], b[n], acc[m][n], 0, 0, 0);
  }

#pragma unroll
  for (int m = 0; m < 4; ++m) {
    int row0 = bm * 128 + wm * 64 + m * 16 + kq * 4;
#pragma unroll
    for (int n = 0; n < 4; ++n) {
      int col = bn * 128 + wn * 64 + n * 16 + lr;
#pragma unroll
      for (int e = 0; e < 4; ++e)
        C[(size_t)(row0 + e) * ldc + col] = f2b(acc[m][n][e]);
    }
  }
}

// ---------------- gather: h_out[v] = relu( sum_e XW[src_e, r_e] + XW[v,self] + b ) ---
// Wave per node; 2 fp32 accumulators per lane; meta preload + readlane broadcast;
// 8/4-deep independent loads. No switch, no atomics.
__global__ __launch_bounds__(256) void gather_out(const uint* __restrict__ XWu,
                                                  const uint* __restrict__ meta,
                                                  const int* __restrict__ offs,
                                                  const int* __restrict__ deg,
                                                  const float* __restrict__ bias,
                                                  uint* __restrict__ hout) {
  int node = (blockIdx.x * 256 + threadIdx.x) >> 6;
  int ln = threadIdx.x & 63;
  int start = __builtin_amdgcn_readfirstlane(offs[node]);
  int ne = __builtin_amdgcn_readfirstlane(deg[node]);
  // issue self + bias loads early; they complete under the edge loop
  uint sv = XWu[(size_t)node * 576 + 512 + ln];
  float2 bv = ((const float2*)bias)[ln];
  float acc0 = 0.f, acc1 = 0.f;

  for (int c = 0; c < ne; c += 64) {
    int nc = ne - c;
    if (nc > 64) nc = 64;
    uint mv = meta[start + c + (ln < nc ? ln : nc - 1)];  // wave preload
    int i = 0;
    for (; i + 8 <= nc; i += 8) {
      uint v0 = XWu[(uint)__builtin_amdgcn_readlane((int)mv, i + 0) + ln];
      uint v1 = XWu[(uint)__builtin_amdgcn_readlane((int)mv, i + 1) + ln];
      uint v2 = XWu[(uint)__builtin_amdgcn_readlane((int)mv, i + 2) + ln];
      uint v3 = XWu[(uint)__builtin_amdgcn_readlane((int)mv, i + 3) + ln];
      uint v4 = XWu[(uint)__builtin_amdgcn_readlane((int)mv, i + 4) + ln];
      uint v5 = XWu[(uint)__builtin_amdgcn_readlane((int)mv, i + 5) + ln];
      uint v6 = XWu[(uint)__builtin_amdgcn_readlane((int)mv, i + 6) + ln];
      uint v7 = XWu[(uint)__builtin_amdgcn_readlane((int)mv, i + 7) + ln];
      acc0 += blo(v0); acc1 += bhi(v0);
      acc0 += blo(v1); acc1 += bhi(v1);
      acc0 += blo(v2); acc1 += bhi(v2);
      acc0 += blo(v3); acc1 += bhi(v3);
      acc0 += blo(v4); acc1 += bhi(v4);
      acc0 += blo(v5); acc1 += bhi(v5);
      acc0 += blo(v6); acc1 += bhi(v6);
      acc0 += blo(v7); acc1 += bhi(v7);
    }
    for (; i + 4 <= nc; i += 4) {
      uint v0 = XWu[(uint)__builtin_amdgcn_readlane((int)mv, i + 0) + ln];
      uint v1 = XWu[(uint)__builtin_amdgcn_readlane((int)mv, i + 1) + ln];
      uint v2 = XWu[(uint)__builtin_amdgcn_readlane((int)mv, i + 2) + ln];
      uint v3 = XWu[(uint)__builtin_amdgcn_readlane((int)mv, i + 3) + ln];
      acc0 += blo(v0); acc1 += bhi(v0);
      acc0 += blo(v1); acc1 += bhi(v1);
      acc0 += blo(v2); acc1 += bhi(v2);
      acc0 += blo(v3); acc1 += bhi(v3);
    }
    for (; i < nc; ++i) {
      uint v = XWu[(uint)__builtin_amdgcn_readlane((int)mv, i) + ln];
      acc0 += blo(v); acc1 += bhi(v);
    }
  }

  float r0 = fmaxf(acc0 + blo(sv) + bv.x, 0.f);
  float r1 = fmaxf(acc1 + bhi(sv) + bv.y, 0.f);
  hout[(size_t)node * 64 + ln] = (uint)f2b(r0) | ((uint)f2b(r1) << 16);
}

// ---------------- pool (2-stage) + classifier ----------------
__global__ __launch_bounds__(256) void pool_partial(const ushort* __restrict__ h2,
                                                    float* __restrict__ partial) {
  __shared__ float red[8][128];
  int blk = blockIdx.x, tid = threadIdx.x;
  int c = tid & 31, r = tid >> 5;
  float mx[4] = {0.f, 0.f, 0.f, 0.f};  // post-ReLU >= 0
  const ushort* base = h2 + (size_t)blk * 128 * DIM;
  for (int node = r; node < 128; node += 8) {
    ushort4 v = *(const ushort4*)(base + node * DIM + c * 4);
    mx[0] = fmaxf(mx[0], b2f(v.x));
    mx[1] = fmaxf(mx[1], b2f(v.y));
    mx[2] = fmaxf(mx[2], b2f(v.z));
    mx[3] = fmaxf(mx[3], b2f(v.w));
  }
#pragma unroll
  for (int j = 0; j < 4; ++j) red[r][c * 4 + j] = mx[j];
  __syncthreads();
  if (tid < 128) {
    float m = 0.f;
#pragma unroll
    for (int rr = 0; rr < 8; ++rr) m = fmaxf(m, red[rr][tid]);
    partial[(size_t)blk * 128 + tid] = m;
  }
}
__global__ __launch_bounds__(128) void classify(const float* __restrict__ partial,
                                                const float* __restrict__ Wc,
                                                const float* __restrict__ bc,
                                                float* __restrict__ out) {
  __shared__ float pooled[128];
  int g = blockIdx.x, tid = threadIdx.x;
  const float* p = partial + (size_t)g * 8 * 128;
  float m = 0.f;
#pragma unroll
  for (int b = 0; b < 8; ++b) m = fmaxf(m, p[b * 128 + tid]);
  pooled[tid] = m;
  __syncthreads();
  if (tid < 10) {
    float s = bc[tid];
    for (int d = 0; d < DIM; ++d) s += pooled[d] * Wc[d * 10 + tid];
    out[g * 10 + tid] = s;
  }
}

extern "C" void kernel_launch(void* const* d_in, const int* in_sizes, int n_in,
                              void* d_out, int out_size, void* d_ws, size_t ws_size,
                              hipStream_t stream) {
  const float* h       = (const float*)d_in[0];
  const float* W1      = (const float*)d_in[1];
  const float* W1_self = (const float*)d_in[2];
  const float* b1      = (const float*)d_in[3];
  const float* W2      = (const float*)d_in[4];
  const float* W2_self = (const float*)d_in[5];
  const float* b2      = (const float*)d_in[6];
  const float* Wc      = (const float*)d_in[7];
  const float* bc      = (const float*)d_in[8];
  const int* src   = (const int*)d_in[9];
  const int* dst   = (const int*)d_in[10];
  const int* etype = (const int*)d_in[11];
  float* out = (float*)d_out;

  char* ws = (char*)d_ws;
  ushort* XW     = (ushort*)(ws);
  ushort* hb     = (ushort*)(ws + 150994944);
  ushort* h1b    = (ushort*)(ws + 167772160);
  ushort* hb2    = (ushort*)(ws + 184549376);
  ushort* Wt1c   = (ushort*)(ws + 201326592);
  ushort* Wt2c   = (ushort*)(ws + 201621504);
  int*    deg    = (int*)(ws + 201916416);
  int*    offs   = (int*)(ws + 202178560);
  int*    cursor = (int*)(ws + 202440704);
  int*    bsum   = (int*)(ws + 202702848);
  uint*   meta   = (uint*)(ws + 202703872);
  float*  partial= (float*)(ws + 205849600);

  const int n4_h = N_NODES * DIM / 4;        // 2,097,152
  const int g_h = n4_h / 256;                // 8192
  const int g_edge = (N_EDGES + 255) / 256;  // 3072
  const int g_sliced = g_edge * 8;           // 24576 (8 XCD slices)
  const int g_gather = N_NODES / 4;          // 16384 (4 waves/block)
  dim3 gemm_grid(N_NODES / 128, NT);

  // --- prep ---
  f32_to_bf16_vec<<<g_h, 256, 0, stream>>>(h, hb, n4_h);
  wconv_all<<<18, 256, 0, stream>>>(W1, W1_self, W2, W2_self, Wt1c, Wt2c);

  // --- CSR by dst (shared by both layers), XCD-sliced scatters ---
  hipMemsetAsync(deg, 0, N_NODES * sizeof(int), stream);
  hist_sliced<<<g_sliced, 256, 0, stream>>>(dst, deg);
  scan_block<<<256, 256, 0, stream>>>(deg, offs, bsum);
  scan_bsum<<<1, 256, 0, stream>>>(bsum);
  add_offs<<<256, 256, 0, stream>>>(offs, bsum, cursor);
  fill_meta_sliced<<<g_sliced, 256, 0, stream>>>(src, dst, etype, cursor, meta);

  // --- layer 1: XW = hb @ Wcat1 ; h1 = relu(gather + self + b1) ---
  gemm128<<<gemm_grid, 256, 0, stream>>>(hb, Wt1c, XW, XW_LD);
  gather_out<<<g_gather, 256, 0, stream>>>((const uint*)XW, meta, offs, deg, b1, (uint*)h1b);

  // --- layer 2 ---
  gemm128<<<gemm_grid, 256, 0, stream>>>(h1b, Wt2c, XW, XW_LD);
  gather_out<<<g_gather, 256, 0, stream>>>((const uint*)XW, meta, offs, deg, b2, (uint*)hb2);

  // --- pool + classify ---
  pool_partial<<<512, 256, 0, stream>>>(hb2, partial);
  classify<<<N_GRAPHS, 128, 0, stream>>>(partial, Wc, bc, out);

  (void)in_sizes; (void)n_in; (void)out_size; (void)ws_size;
}